// Round 4
// baseline (410.921 us; speedup 1.0000x reference)
//
#include <hip/hip_runtime.h>

#define N_NODES 50000
#define N_EDGES 800000
#define N_GRAPHS 512
#define DIM 128

typedef unsigned int uint;
typedef unsigned short ushort;

// bf16 helpers (RNE pack, cheap unpack)
__device__ __forceinline__ ushort f2bf(float f) {
    uint u = __float_as_uint(f);
    return (ushort)((u + 0x7fffu + ((u >> 16) & 1u)) >> 16);
}
__device__ __forceinline__ float bflo(uint p) { return __uint_as_float(p << 16); }
__device__ __forceinline__ float bfhi(uint p) { return __uint_as_float(p & 0xffff0000u); }

// ---------------- graph preprocessing ----------------

__global__ void init_deg_k(int* deg, int n) {
    int i = blockIdx.x * blockDim.x + threadIdx.x;
    if (i < n) deg[i] = 1;  // self-loop
}

__global__ void count_k(const int* __restrict__ dst, int* deg, int e) {
    int i = blockIdx.x * blockDim.x + threadIdx.x;
    if (i < e) atomicAdd(&deg[dst[i]], 1);
}

__global__ void dis_k(const int* __restrict__ deg, float* dis, int n) {
    int i = blockIdx.x * blockDim.x + threadIdx.x;
    if (i < n) dis[i] = rsqrtf((float)deg[i]);
}

// ---------------- multi-block exclusive scan (3 phases) ----------------
#define SCAN_TPB 256
#define SCAN_ELEMS 2048
#define SCAN_BLOCKS ((N_NODES + SCAN_ELEMS - 1) / SCAN_ELEMS)   // 25

__global__ __launch_bounds__(SCAN_TPB) void scan1_k(const int* __restrict__ deg,
                                                    int* __restrict__ local,
                                                    int* __restrict__ partials, int n) {
    __shared__ int lds[SCAN_ELEMS];
    __shared__ int sums[SCAN_TPB];
    int t = threadIdx.x;
    int base = blockIdx.x * SCAN_ELEMS;
#pragma unroll
    for (int i = 0; i < 8; i++) {
        int idx = base + t + i * SCAN_TPB;
        lds[t + i * SCAN_TPB] = (idx < n) ? deg[idx] : 0;
    }
    __syncthreads();
    int off = t * 8;
    int s = 0;
#pragma unroll
    for (int i = 0; i < 8; i++) s += lds[off + i];
    sums[t] = s;
    __syncthreads();
    for (int o = 1; o < SCAN_TPB; o <<= 1) {
        int v = sums[t];
        int add = (t >= o) ? sums[t - o] : 0;
        __syncthreads();
        sums[t] = v + add;
        __syncthreads();
    }
    int run = (t == 0) ? 0 : sums[t - 1];
#pragma unroll
    for (int i = 0; i < 8; i++) {
        int v = lds[off + i];
        lds[off + i] = run;
        run += v;
    }
    if (t == SCAN_TPB - 1) partials[blockIdx.x] = run;
    __syncthreads();
#pragma unroll
    for (int i = 0; i < 8; i++) {
        int idx = base + t + i * SCAN_TPB;
        if (idx < n) local[idx] = lds[t + i * SCAN_TPB];
    }
}

__global__ void scan2_k(int* partials) {
    if (threadIdx.x == 0) {
        int run = 0;
        for (int b = 0; b < SCAN_BLOCKS; b++) {
            int v = partials[b];
            partials[b] = run;
            run += v;
        }
    }
}

__global__ void scan3_k(int* __restrict__ row_ptr, const int* __restrict__ partials,
                        int* __restrict__ cursor, int n, int total) {
    int i = blockIdx.x * blockDim.x + threadIdx.x;
    if (i < n) {
        int r = row_ptr[i] + partials[i / SCAN_ELEMS];
        row_ptr[i] = r;
        cursor[i] = r;
    }
    if (i == 0) row_ptr[n] = total;
}

// fill: store ONLY col (weights recomputed in agg from dis[]) -> half the scatter,
// and the 3.4 MB target fits in a single XCD L2 (minimal writeback amplification)
__global__ void fill_k(const int* __restrict__ src, const int* __restrict__ dst,
                       int* cursor, int* col, int e, int n) {
    int i = blockIdx.x * blockDim.x + threadIdx.x;
    if (i < e) {
        int s = src[i], d = dst[i];
        int pos = atomicAdd(&cursor[d], 1);
        col[pos] = s;
    } else if (i < e + n) {
        int v = i - e;
        int pos = atomicAdd(&cursor[v], 1);
        col[pos] = v;   // self-loop: weight dis[v]^2 falls out of w=dis[col]*dis[node]
    }
}

// ---------------- dense GEMM: H[n x 128](bf16) = X[n x 128] @ W[128 x 128] ----------------

#define GEMM_ROWS 32

template <typename TIn>
__global__ __launch_bounds__(256) void gemm_k(const TIn* __restrict__ X,
                                              const float* __restrict__ W,
                                              ushort* __restrict__ H, int n) {
    __shared__ float Ws[64 * 128];          // 32 KB
    __shared__ float Xs[GEMM_ROWS * 128];   // 16 KB

    int t = threadIdx.x;
    int row0 = blockIdx.x * GEMM_ROWS;

    for (int i = t; i < GEMM_ROWS * 32; i += 256) {
        int r = i >> 5, q = i & 31;
        float4 v = make_float4(0.f, 0.f, 0.f, 0.f);
        if (row0 + r < n) {
            if constexpr (sizeof(TIn) == 4) {
                v = ((const float4*)X)[(size_t)(row0 + r) * 32 + q];
            } else {
                uint2 p = ((const uint2*)X)[(size_t)(row0 + r) * 32 + q];
                v = make_float4(bflo(p.x), bfhi(p.x), bflo(p.y), bfhi(p.y));
            }
        }
        ((float4*)Xs)[i] = v;
    }

    int tc = t & 31, tr = t >> 5;
    int j0 = tc * 4, r0 = tr * 4;
    float acc[4][4];
#pragma unroll
    for (int a = 0; a < 4; a++)
#pragma unroll
        for (int b = 0; b < 4; b++) acc[a][b] = 0.f;

    for (int kp = 0; kp < 2; kp++) {
        int k0 = kp * 64;
        __syncthreads();
        for (int i = t; i < 64 * 32; i += 256)
            ((float4*)Ws)[i] = ((const float4*)W)[k0 * 32 + i];
        __syncthreads();
#pragma unroll 4
        for (int k = 0; k < 64; k++) {
            float4 wv = *(const float4*)(Ws + k * 128 + j0);
#pragma unroll
            for (int a = 0; a < 4; a++) {
                float xv = Xs[(r0 + a) * 128 + k0 + k];
                acc[a][0] += xv * wv.x;
                acc[a][1] += xv * wv.y;
                acc[a][2] += xv * wv.z;
                acc[a][3] += xv * wv.w;
            }
        }
    }

#pragma unroll
    for (int a = 0; a < 4; a++) {
        int row = row0 + r0 + a;
        if (row < n) {
            uint o0 = (uint)f2bf(acc[a][0]) | ((uint)f2bf(acc[a][1]) << 16);
            uint o1 = (uint)f2bf(acc[a][2]) | ((uint)f2bf(acc[a][3]) << 16);
            *(uint2*)(H + (size_t)row * DIM + j0) = make_uint2(o0, o1);
        }
    }
}

// ---------------- CSR aggregation + bias + ReLU (bf16 in/out, fp32 accum) ----------------
// 2 nodes per wave (32 lanes x uint2 = 256B row), 4-edge unroll for MLP.
// weight computed on the fly: w = dis[col[e]] * dis[node]

__global__ __launch_bounds__(256) void agg_k(const ushort* __restrict__ H,
                                             const int* __restrict__ row_ptr,
                                             const int* __restrict__ col,
                                             const float* __restrict__ dis,
                                             const float* __restrict__ bias,
                                             ushort* __restrict__ Out, int n) {
    int node = blockIdx.x * 8 + (threadIdx.x >> 5);
    int lane = threadIdx.x & 31;        // 32 lanes per node, 4 features/lane
    if (node >= n) return;
    float dn = dis[node];
    int beg = row_ptr[node], end = row_ptr[node + 1];
    float a0 = 0.f, a1 = 0.f, a2 = 0.f, a3 = 0.f;
    int e = beg;
    for (; e + 3 < end; e += 4) {
        int c0 = col[e], c1 = col[e + 1], c2 = col[e + 2], c3 = col[e + 3];
        float w0 = dis[c0], w1 = dis[c1], w2 = dis[c2], w3 = dis[c3];
        uint2 p0 = *(const uint2*)(H + (size_t)c0 * DIM + lane * 4);
        uint2 p1 = *(const uint2*)(H + (size_t)c1 * DIM + lane * 4);
        uint2 p2 = *(const uint2*)(H + (size_t)c2 * DIM + lane * 4);
        uint2 p3 = *(const uint2*)(H + (size_t)c3 * DIM + lane * 4);
        a0 += w0 * bflo(p0.x) + w1 * bflo(p1.x) + w2 * bflo(p2.x) + w3 * bflo(p3.x);
        a1 += w0 * bfhi(p0.x) + w1 * bfhi(p1.x) + w2 * bfhi(p2.x) + w3 * bfhi(p3.x);
        a2 += w0 * bflo(p0.y) + w1 * bflo(p1.y) + w2 * bflo(p2.y) + w3 * bflo(p3.y);
        a3 += w0 * bfhi(p0.y) + w1 * bfhi(p1.y) + w2 * bfhi(p2.y) + w3 * bfhi(p3.y);
    }
    for (; e < end; e++) {
        int c = col[e];
        float w = dis[c];
        uint2 p = *(const uint2*)(H + (size_t)c * DIM + lane * 4);
        a0 += w * bflo(p.x);
        a1 += w * bfhi(p.x);
        a2 += w * bflo(p.y);
        a3 += w * bfhi(p.y);
    }
    int d0 = lane * 4;
    a0 = fmaxf(a0 * dn + bias[d0], 0.f);
    a1 = fmaxf(a1 * dn + bias[d0 + 1], 0.f);
    a2 = fmaxf(a2 * dn + bias[d0 + 2], 0.f);
    a3 = fmaxf(a3 * dn + bias[d0 + 3], 0.f);
    uint o0 = (uint)f2bf(a0) | ((uint)f2bf(a1) << 16);
    uint o1 = (uint)f2bf(a2) | ((uint)f2bf(a3) << 16);
    *(uint2*)(Out + (size_t)node * DIM + d0) = make_uint2(o0, o1);
}

// ---------------- global add pool (batch_vec sorted, bf16 in, fp32 out) ----------------

__global__ void pool_k(const ushort* __restrict__ H, const int* __restrict__ batch,
                       float* Out, int n) {
    int d = threadIdx.x;
    int n0 = blockIdx.x * 64;
    int gcur = -1;
    float s = 0.f;
    for (int i = 0; i < 64; i++) {
        int node = n0 + i;
        if (node >= n) break;
        int g = batch[node];
        if (g != gcur) {
            if (gcur >= 0) atomicAdd(&Out[gcur * DIM + d], s);
            gcur = g;
            s = 0.f;
        }
        s += bflo((uint)H[(size_t)node * DIM + d]);
    }
    if (gcur >= 0) atomicAdd(&Out[gcur * DIM + d], s);
}

// ---------------- launch ----------------

extern "C" void kernel_launch(void* const* d_in, const int* in_sizes, int n_in,
                              void* d_out, int out_size, void* d_ws, size_t ws_size,
                              hipStream_t stream) {
    const float* x  = (const float*)d_in[0];
    const float* W1 = (const float*)d_in[1];
    const float* b1 = (const float*)d_in[2];
    const float* W2 = (const float*)d_in[3];
    const float* b2 = (const float*)d_in[4];
    const float* W3 = (const float*)d_in[5];
    const float* b3 = (const float*)d_in[6];
    const int*   ei = (const int*)d_in[7];
    const int*   bv = (const int*)d_in[8];
    float* out = (float*)d_out;

    const int N = N_NODES, E = N_EDGES;

    char* p = (char*)d_ws;
    auto alloc = [&](size_t bytes) -> void* {
        void* r = (void*)p;
        p += (bytes + 255) & ~(size_t)255;
        return r;
    };
    int*    deg      = (int*)alloc((size_t)N * 4);
    int*    row_ptr  = (int*)alloc((size_t)(N + 1) * 4);
    int*    cursor   = (int*)alloc((size_t)N * 4);
    int*    partials = (int*)alloc((size_t)SCAN_BLOCKS * 4);
    float*  dis      = (float*)alloc((size_t)N * 4);
    int*    col      = (int*)alloc((size_t)(E + N) * 4);
    ushort* B1       = (ushort*)alloc((size_t)N * DIM * 2);
    ushort* B2       = (ushort*)alloc((size_t)N * DIM * 2);

    const int* src = ei;
    const int* dst = ei + E;

    hipMemsetAsync(d_out, 0, (size_t)N_GRAPHS * DIM * sizeof(float), stream);

    init_deg_k<<<(N + 255) / 256, 256, 0, stream>>>(deg, N);
    count_k<<<(E + 255) / 256, 256, 0, stream>>>(dst, deg, E);
    dis_k<<<(N + 255) / 256, 256, 0, stream>>>(deg, dis, N);
    scan1_k<<<SCAN_BLOCKS, SCAN_TPB, 0, stream>>>(deg, row_ptr, partials, N);
    scan2_k<<<1, 64, 0, stream>>>(partials);
    scan3_k<<<(N + 255) / 256, 256, 0, stream>>>(row_ptr, partials, cursor, N, E + N);
    fill_k<<<(E + N + 255) / 256, 256, 0, stream>>>(src, dst, cursor, col, E, N);

    int gemm_grid = (N + GEMM_ROWS - 1) / GEMM_ROWS;
    int agg_grid  = (N + 7) / 8;

    gemm_k<float><<<gemm_grid, 256, 0, stream>>>(x,  W1, B1, N);
    agg_k<<<agg_grid, 256, 0, stream>>>(B1, row_ptr, col, dis, b1, B2, N);

    gemm_k<ushort><<<gemm_grid, 256, 0, stream>>>(B2, W2, B1, N);
    agg_k<<<agg_grid, 256, 0, stream>>>(B1, row_ptr, col, dis, b2, B2, N);

    gemm_k<ushort><<<gemm_grid, 256, 0, stream>>>(B2, W3, B1, N);
    agg_k<<<agg_grid, 256, 0, stream>>>(B1, row_ptr, col, dis, b3, B2, N);

    pool_k<<<(N + 63) / 64, 128, 0, stream>>>(B2, bv, out, N);
}

// Round 5
// 399.914 us; speedup vs baseline: 1.0275x; 1.0275x over previous
//
#include <hip/hip_runtime.h>

#define N_NODES 50000
#define N_EDGES 800000
#define N_GRAPHS 512
#define DIM 128

typedef unsigned int uint;
typedef unsigned short ushort;

// bf16 helpers (RNE pack, cheap unpack)
__device__ __forceinline__ ushort f2bf(float f) {
    uint u = __float_as_uint(f);
    return (ushort)((u + 0x7fffu + ((u >> 16) & 1u)) >> 16);
}
__device__ __forceinline__ float bflo(uint p) { return __uint_as_float(p << 16); }
__device__ __forceinline__ float bfhi(uint p) { return __uint_as_float(p & 0xffff0000u); }

// ---------------- graph preprocessing ----------------
// counters padded to 1 per 64B line to kill same-line atomic serialization

__global__ void count_k(const int* __restrict__ dst, int* deg_pad, int e) {
    int i = blockIdx.x * blockDim.x + threadIdx.x;
    if (i < e) atomicAdd(&deg_pad[dst[i] << 4], 1);
}

// ---------------- multi-block exclusive scan (3 phases) ----------------
#define SCAN_TPB 256
#define SCAN_ELEMS 2048
#define SCAN_BLOCKS ((N_NODES + SCAN_ELEMS - 1) / SCAN_ELEMS)   // 25

__global__ __launch_bounds__(SCAN_TPB) void scan1_k(const int* __restrict__ deg_pad,
                                                    int* __restrict__ local,
                                                    int* __restrict__ partials, int n) {
    __shared__ int lds[SCAN_ELEMS];
    __shared__ int sums[SCAN_TPB];
    int t = threadIdx.x;
    int base = blockIdx.x * SCAN_ELEMS;
#pragma unroll
    for (int i = 0; i < 8; i++) {
        int idx = base + t + i * SCAN_TPB;
        lds[t + i * SCAN_TPB] = (idx < n) ? deg_pad[idx << 4] : 0;
    }
    __syncthreads();
    int off = t * 8;
    int s = 0;
#pragma unroll
    for (int i = 0; i < 8; i++) s += lds[off + i];
    sums[t] = s;
    __syncthreads();
    for (int o = 1; o < SCAN_TPB; o <<= 1) {
        int v = sums[t];
        int add = (t >= o) ? sums[t - o] : 0;
        __syncthreads();
        sums[t] = v + add;
        __syncthreads();
    }
    int run = (t == 0) ? 0 : sums[t - 1];
#pragma unroll
    for (int i = 0; i < 8; i++) {
        int v = lds[off + i];
        lds[off + i] = run;
        run += v;
    }
    if (t == SCAN_TPB - 1) partials[blockIdx.x] = run;
    __syncthreads();
#pragma unroll
    for (int i = 0; i < 8; i++) {
        int idx = base + t + i * SCAN_TPB;
        if (idx < n) local[idx] = lds[t + i * SCAN_TPB];
    }
}

__global__ void scan2_k(int* partials) {
    if (threadIdx.x == 0) {
        int run = 0;
        for (int b = 0; b < SCAN_BLOCKS; b++) {
            int v = partials[b];
            partials[b] = run;
            run += v;
        }
    }
}

// phase 3: finalize row_ptr, init padded cursor, compute dis (self-loop adds 1 to deg)
__global__ void scan3_k(int* __restrict__ row_ptr, const int* __restrict__ partials,
                        int* __restrict__ cursor_pad, const int* __restrict__ deg_pad,
                        float* __restrict__ dis, int n, int total) {
    int i = blockIdx.x * blockDim.x + threadIdx.x;
    if (i < n) {
        int r = row_ptr[i] + partials[i / SCAN_ELEMS];
        row_ptr[i] = r;
        cursor_pad[i << 4] = r;
        dis[i] = rsqrtf((float)(deg_pad[i << 4] + 1));
    }
    if (i == 0) row_ptr[n] = total;
}

// fill: only real edges (self-loops handled analytically in agg)
__global__ void fill_k(const int* __restrict__ src, const int* __restrict__ dst,
                       int* cursor_pad, int* col, int e) {
    int i = blockIdx.x * blockDim.x + threadIdx.x;
    if (i < e) {
        int s = src[i], d = dst[i];
        int pos = atomicAdd(&cursor_pad[d << 4], 1);
        col[pos] = s;
    }
}

// ---------------- dense GEMM: H[n x 128](bf16) = X[n x 128] @ W[128 x 128] ----------------

#define GEMM_ROWS 32

template <typename TIn>
__global__ __launch_bounds__(256) void gemm_k(const TIn* __restrict__ X,
                                              const float* __restrict__ W,
                                              ushort* __restrict__ H, int n) {
    __shared__ float Ws[64 * 128];          // 32 KB
    __shared__ float Xs[GEMM_ROWS * 128];   // 16 KB

    int t = threadIdx.x;
    int row0 = blockIdx.x * GEMM_ROWS;

    for (int i = t; i < GEMM_ROWS * 32; i += 256) {
        int r = i >> 5, q = i & 31;
        float4 v = make_float4(0.f, 0.f, 0.f, 0.f);
        if (row0 + r < n) {
            if constexpr (sizeof(TIn) == 4) {
                v = ((const float4*)X)[(size_t)(row0 + r) * 32 + q];
            } else {
                uint2 p = ((const uint2*)X)[(size_t)(row0 + r) * 32 + q];
                v = make_float4(bflo(p.x), bfhi(p.x), bflo(p.y), bfhi(p.y));
            }
        }
        ((float4*)Xs)[i] = v;
    }

    int tc = t & 31, tr = t >> 5;
    int j0 = tc * 4, r0 = tr * 4;
    float acc[4][4];
#pragma unroll
    for (int a = 0; a < 4; a++)
#pragma unroll
        for (int b = 0; b < 4; b++) acc[a][b] = 0.f;

    for (int kp = 0; kp < 2; kp++) {
        int k0 = kp * 64;
        __syncthreads();
        for (int i = t; i < 64 * 32; i += 256)
            ((float4*)Ws)[i] = ((const float4*)W)[k0 * 32 + i];
        __syncthreads();
#pragma unroll 4
        for (int k = 0; k < 64; k++) {
            float4 wv = *(const float4*)(Ws + k * 128 + j0);
#pragma unroll
            for (int a = 0; a < 4; a++) {
                float xv = Xs[(r0 + a) * 128 + k0 + k];
                acc[a][0] += xv * wv.x;
                acc[a][1] += xv * wv.y;
                acc[a][2] += xv * wv.z;
                acc[a][3] += xv * wv.w;
            }
        }
    }

#pragma unroll
    for (int a = 0; a < 4; a++) {
        int row = row0 + r0 + a;
        if (row < n) {
            uint o0 = (uint)f2bf(acc[a][0]) | ((uint)f2bf(acc[a][1]) << 16);
            uint o1 = (uint)f2bf(acc[a][2]) | ((uint)f2bf(acc[a][3]) << 16);
            *(uint2*)(H + (size_t)row * DIM + j0) = make_uint2(o0, o1);
        }
    }
}

// ---------------- CSR aggregation + bias + ReLU (bf16 in/out, fp32 accum) ----------------
// 2 nodes per wave (32 lanes x uint2 = 256B row), 4-edge unroll.
// self-loop handled analytically: acc starts at dis[node]*h[node]; final scale by dis[node].

__global__ __launch_bounds__(256) void agg_k(const ushort* __restrict__ H,
                                             const int* __restrict__ row_ptr,
                                             const int* __restrict__ col,
                                             const float* __restrict__ dis,
                                             const float* __restrict__ bias,
                                             ushort* __restrict__ Out, int n) {
    int node = blockIdx.x * 8 + (threadIdx.x >> 5);
    int lane = threadIdx.x & 31;        // 32 lanes per node, 4 features/lane
    if (node >= n) return;
    float dn = dis[node];
    int beg = row_ptr[node], end = row_ptr[node + 1];
    uint2 pw = *(const uint2*)(H + (size_t)node * DIM + lane * 4);  // own row (self-loop)
    float a0 = dn * bflo(pw.x), a1 = dn * bfhi(pw.x);
    float a2 = dn * bflo(pw.y), a3 = dn * bfhi(pw.y);
    int e = beg;
    for (; e + 3 < end; e += 4) {
        int c0 = col[e], c1 = col[e + 1], c2 = col[e + 2], c3 = col[e + 3];
        float w0 = dis[c0], w1 = dis[c1], w2 = dis[c2], w3 = dis[c3];
        uint2 p0 = *(const uint2*)(H + (size_t)c0 * DIM + lane * 4);
        uint2 p1 = *(const uint2*)(H + (size_t)c1 * DIM + lane * 4);
        uint2 p2 = *(const uint2*)(H + (size_t)c2 * DIM + lane * 4);
        uint2 p3 = *(const uint2*)(H + (size_t)c3 * DIM + lane * 4);
        a0 += w0 * bflo(p0.x) + w1 * bflo(p1.x) + w2 * bflo(p2.x) + w3 * bflo(p3.x);
        a1 += w0 * bfhi(p0.x) + w1 * bfhi(p1.x) + w2 * bfhi(p2.x) + w3 * bfhi(p3.x);
        a2 += w0 * bflo(p0.y) + w1 * bflo(p1.y) + w2 * bflo(p2.y) + w3 * bflo(p3.y);
        a3 += w0 * bfhi(p0.y) + w1 * bfhi(p1.y) + w2 * bfhi(p2.y) + w3 * bfhi(p3.y);
    }
    for (; e < end; e++) {
        int c = col[e];
        float w = dis[c];
        uint2 p = *(const uint2*)(H + (size_t)c * DIM + lane * 4);
        a0 += w * bflo(p.x);
        a1 += w * bfhi(p.x);
        a2 += w * bflo(p.y);
        a3 += w * bfhi(p.y);
    }
    int d0 = lane * 4;
    a0 = fmaxf(a0 * dn + bias[d0], 0.f);
    a1 = fmaxf(a1 * dn + bias[d0 + 1], 0.f);
    a2 = fmaxf(a2 * dn + bias[d0 + 2], 0.f);
    a3 = fmaxf(a3 * dn + bias[d0 + 3], 0.f);
    uint o0 = (uint)f2bf(a0) | ((uint)f2bf(a1) << 16);
    uint o1 = (uint)f2bf(a2) | ((uint)f2bf(a3) << 16);
    *(uint2*)(Out + (size_t)node * DIM + d0) = make_uint2(o0, o1);
}

// ---------------- global add pool (batch_vec sorted, bf16 in, fp32 out) ----------------

__global__ void pool_k(const ushort* __restrict__ H, const int* __restrict__ batch,
                       float* Out, int n) {
    int d = threadIdx.x;
    int n0 = blockIdx.x * 64;
    int gcur = -1;
    float s = 0.f;
    for (int i = 0; i < 64; i++) {
        int node = n0 + i;
        if (node >= n) break;
        int g = batch[node];
        if (g != gcur) {
            if (gcur >= 0) atomicAdd(&Out[gcur * DIM + d], s);
            gcur = g;
            s = 0.f;
        }
        s += bflo((uint)H[(size_t)node * DIM + d]);
    }
    if (gcur >= 0) atomicAdd(&Out[gcur * DIM + d], s);
}

// ---------------- launch ----------------

extern "C" void kernel_launch(void* const* d_in, const int* in_sizes, int n_in,
                              void* d_out, int out_size, void* d_ws, size_t ws_size,
                              hipStream_t stream) {
    const float* x  = (const float*)d_in[0];
    const float* W1 = (const float*)d_in[1];
    const float* b1 = (const float*)d_in[2];
    const float* W2 = (const float*)d_in[3];
    const float* b2 = (const float*)d_in[4];
    const float* W3 = (const float*)d_in[5];
    const float* b3 = (const float*)d_in[6];
    const int*   ei = (const int*)d_in[7];
    const int*   bv = (const int*)d_in[8];
    float* out = (float*)d_out;

    const int N = N_NODES, E = N_EDGES;

    char* p = (char*)d_ws;
    auto alloc = [&](size_t bytes) -> void* {
        void* r = (void*)p;
        p += (bytes + 255) & ~(size_t)255;
        return r;
    };
    int*    deg_pad    = (int*)alloc((size_t)N * 16 * 4);   // 1 counter per 64B line
    int*    cursor_pad = (int*)alloc((size_t)N * 16 * 4);
    int*    row_ptr    = (int*)alloc((size_t)(N + 1) * 4);
    int*    partials   = (int*)alloc((size_t)SCAN_BLOCKS * 4);
    float*  dis        = (float*)alloc((size_t)N * 4);
    int*    col        = (int*)alloc((size_t)E * 4);
    ushort* B1         = (ushort*)alloc((size_t)N * DIM * 2);
    ushort* B2         = (ushort*)alloc((size_t)N * DIM * 2);

    const int* src = ei;
    const int* dst = ei + E;

    hipMemsetAsync(d_out, 0, (size_t)N_GRAPHS * DIM * sizeof(float), stream);
    hipMemsetAsync(deg_pad, 0, (size_t)N * 16 * 4, stream);

    count_k<<<(E + 255) / 256, 256, 0, stream>>>(dst, deg_pad, E);
    scan1_k<<<SCAN_BLOCKS, SCAN_TPB, 0, stream>>>(deg_pad, row_ptr, partials, N);
    scan2_k<<<1, 64, 0, stream>>>(partials);
    scan3_k<<<(N + 255) / 256, 256, 0, stream>>>(row_ptr, partials, cursor_pad, deg_pad,
                                                 dis, N, E);
    fill_k<<<(E + 255) / 256, 256, 0, stream>>>(src, dst, cursor_pad, col, E);

    int gemm_grid = (N + GEMM_ROWS - 1) / GEMM_ROWS;
    int agg_grid  = (N + 7) / 8;

    gemm_k<float><<<gemm_grid, 256, 0, stream>>>(x,  W1, B1, N);
    agg_k<<<agg_grid, 256, 0, stream>>>(B1, row_ptr, col, dis, b1, B2, N);

    gemm_k<ushort><<<gemm_grid, 256, 0, stream>>>(B2, W2, B1, N);
    agg_k<<<agg_grid, 256, 0, stream>>>(B1, row_ptr, col, dis, b2, B2, N);

    gemm_k<ushort><<<gemm_grid, 256, 0, stream>>>(B2, W3, B1, N);
    agg_k<<<agg_grid, 256, 0, stream>>>(B1, row_ptr, col, dis, b3, B2, N);

    pool_k<<<(N + 63) / 64, 128, 0, stream>>>(B2, bv, out, N);
}

// Round 6
// 354.898 us; speedup vs baseline: 1.1579x; 1.1268x over previous
//
#include <hip/hip_runtime.h>

#define N_NODES 50000
#define N_EDGES 800000
#define N_GRAPHS 512
#define DIM 128

#define BW_LOG 9
#define BWID 512                                  // nodes per bucket
#define NB ((N_NODES + BWID - 1) / BWID)          // 98
#define CHUNK 4096                                // edges per phase-A block
#define NCHUNK ((N_EDGES + CHUNK - 1) / CHUNK)    // 196

typedef unsigned int uint;
typedef unsigned short ushort;

// bf16 helpers (RNE pack, cheap unpack)
__device__ __forceinline__ ushort f2bf(float f) {
    uint u = __float_as_uint(f);
    return (ushort)((u + 0x7fffu + ((u >> 16) & 1u)) >> 16);
}
__device__ __forceinline__ float bflo(uint p) { return __uint_as_float(p << 16); }
__device__ __forceinline__ float bfhi(uint p) { return __uint_as_float(p & 0xffff0000u); }

// ---------------- CSR build: bucket-sorted, write-amplification-free ----------------

// phase A1: coarse bucket histogram (LDS-staged; ~19K global atomics total)
__global__ __launch_bounds__(256) void bhist_k(const int* __restrict__ dst,
                                               int* __restrict__ bcnt_pad, int e) {
    __shared__ int h[NB];
    int t = threadIdx.x;
    for (int i = t; i < NB; i += 256) h[i] = 0;
    __syncthreads();
    int base = blockIdx.x * CHUNK;
    for (int i = t; i < CHUNK; i += 256) {
        int idx = base + i;
        if (idx < e) atomicAdd(&h[dst[idx] >> BW_LOG], 1);
    }
    __syncthreads();
    for (int i = t; i < NB; i += 256)
        if (h[i]) atomicAdd(&bcnt_pad[i << 4], h[i]);
}

// phase A2: scan 98 bucket counts, init bucket cursors
__global__ void bscan_k(const int* __restrict__ bcnt_pad, int* __restrict__ bbase,
                        int* __restrict__ bcur_pad) {
    if (threadIdx.x == 0) {
        int run = 0;
        for (int b = 0; b < NB; b++) {
            bbase[b] = run;
            bcur_pad[b << 4] = run;
            run += bcnt_pad[b << 4];
        }
        bbase[NB] = run;
    }
}

// phase A3: bucket-partition edges; writes are contiguous runs per (block,bucket)
// packed record: (src << 9) | (dst & 511)   [src < 65536, fits 16 bits]
__global__ __launch_bounds__(256) void bscat_k(const int* __restrict__ src,
                                               const int* __restrict__ dst,
                                               int* __restrict__ bcur_pad,
                                               uint* __restrict__ stage, int e) {
    __shared__ int h[NB];
    __shared__ int bb[NB];
    __shared__ int lc[NB];
    int t = threadIdx.x;
    for (int i = t; i < NB; i += 256) h[i] = 0;
    __syncthreads();
    int base = blockIdx.x * CHUNK;
    for (int i = t; i < CHUNK; i += 256) {
        int idx = base + i;
        if (idx < e) atomicAdd(&h[dst[idx] >> BW_LOG], 1);
    }
    __syncthreads();
    for (int i = t; i < NB; i += 256) {
        int c = h[i];
        bb[i] = c ? atomicAdd(&bcur_pad[i << 4], c) : 0;
        lc[i] = 0;
    }
    __syncthreads();
    for (int i = t; i < CHUNK; i += 256) {
        int idx = base + i;
        if (idx < e) {
            int d = dst[idx];
            int b = d >> BW_LOG;
            int r = atomicAdd(&lc[b], 1);
            stage[bb[b] + r] = ((uint)src[idx] << BW_LOG) | (uint)(d & (BWID - 1));
        }
    }
}

// phase B: one block per bucket -> row_ptr, dis, col (scatter confined to ~33KB region)
__global__ __launch_bounds__(256) void csr_k(const uint* __restrict__ stage,
                                             const int* __restrict__ bbase,
                                             int* __restrict__ row_ptr,
                                             float* __restrict__ dis,
                                             int* __restrict__ col) {
    __shared__ int hist[BWID];
    __shared__ int excl[BWID];
    __shared__ int ws[256];
    int b = blockIdx.x, t = threadIdx.x;
    int beg = bbase[b], end = bbase[b + 1];
    for (int i = t; i < BWID; i += 256) hist[i] = 0;
    __syncthreads();
    for (int i = beg + t; i < end; i += 256)
        atomicAdd(&hist[stage[i] & (BWID - 1)], 1);
    __syncthreads();
    // block-wide exclusive scan over 512 (pairs per thread)
    int s = hist[2 * t] + hist[2 * t + 1];
    ws[t] = s;
    __syncthreads();
    for (int o = 1; o < 256; o <<= 1) {
        int v = ws[t];
        int add = (t >= o) ? ws[t - o] : 0;
        __syncthreads();
        ws[t] = v + add;
        __syncthreads();
    }
    int pre = (t == 0) ? 0 : ws[t - 1];
    excl[2 * t] = pre;
    excl[2 * t + 1] = pre + hist[2 * t];
    __syncthreads();
    int node0 = b * BWID;
    for (int i = t; i < BWID; i += 256) {
        int node = node0 + i;
        if (node < N_NODES) {
            row_ptr[node] = beg + excl[i];
            dis[node] = rsqrtf((float)(hist[i] + 1));   // +1 = self-loop
        } else if (node == N_NODES) {
            row_ptr[node] = beg + excl[i];              // == E (last bucket)
        }
    }
    __syncthreads();
    for (int i = t; i < BWID; i += 256) hist[i] = excl[i];  // reuse as cursor
    __syncthreads();
    for (int i = beg + t; i < end; i += 256) {
        uint p = stage[i];
        int d9 = p & (BWID - 1);
        int r = atomicAdd(&hist[d9], 1);
        col[beg + r] = (int)(p >> BW_LOG);
    }
}

// ---------------- dense GEMM: H[n x 128](bf16) = X[n x 128] @ W[128 x 128] ----------------

#define GEMM_ROWS 32

template <typename TIn>
__global__ __launch_bounds__(256) void gemm_k(const TIn* __restrict__ X,
                                              const float* __restrict__ W,
                                              ushort* __restrict__ H, int n) {
    __shared__ float Ws[64 * 128];          // 32 KB
    __shared__ float Xs[GEMM_ROWS * 128];   // 16 KB

    int t = threadIdx.x;
    int row0 = blockIdx.x * GEMM_ROWS;

    for (int i = t; i < GEMM_ROWS * 32; i += 256) {
        int r = i >> 5, q = i & 31;
        float4 v = make_float4(0.f, 0.f, 0.f, 0.f);
        if (row0 + r < n) {
            if constexpr (sizeof(TIn) == 4) {
                v = ((const float4*)X)[(size_t)(row0 + r) * 32 + q];
            } else {
                uint2 p = ((const uint2*)X)[(size_t)(row0 + r) * 32 + q];
                v = make_float4(bflo(p.x), bfhi(p.x), bflo(p.y), bfhi(p.y));
            }
        }
        ((float4*)Xs)[i] = v;
    }

    int tc = t & 31, tr = t >> 5;
    int j0 = tc * 4, r0 = tr * 4;
    float acc[4][4];
#pragma unroll
    for (int a = 0; a < 4; a++)
#pragma unroll
        for (int b = 0; b < 4; b++) acc[a][b] = 0.f;

    for (int kp = 0; kp < 2; kp++) {
        int k0 = kp * 64;
        __syncthreads();
        for (int i = t; i < 64 * 32; i += 256)
            ((float4*)Ws)[i] = ((const float4*)W)[k0 * 32 + i];
        __syncthreads();
#pragma unroll 4
        for (int k = 0; k < 64; k++) {
            float4 wv = *(const float4*)(Ws + k * 128 + j0);
#pragma unroll
            for (int a = 0; a < 4; a++) {
                float xv = Xs[(r0 + a) * 128 + k0 + k];
                acc[a][0] += xv * wv.x;
                acc[a][1] += xv * wv.y;
                acc[a][2] += xv * wv.z;
                acc[a][3] += xv * wv.w;
            }
        }
    }

#pragma unroll
    for (int a = 0; a < 4; a++) {
        int row = row0 + r0 + a;
        if (row < n) {
            uint o0 = (uint)f2bf(acc[a][0]) | ((uint)f2bf(acc[a][1]) << 16);
            uint o1 = (uint)f2bf(acc[a][2]) | ((uint)f2bf(acc[a][3]) << 16);
            *(uint2*)(H + (size_t)row * DIM + j0) = make_uint2(o0, o1);
        }
    }
}

// ---------------- CSR aggregation + bias + ReLU (bf16 in/out, fp32 accum) ----------------
// self-loop handled analytically: acc starts at dis[node]*h[node]; final scale by dis[node].

__global__ __launch_bounds__(256) void agg_k(const ushort* __restrict__ H,
                                             const int* __restrict__ row_ptr,
                                             const int* __restrict__ col,
                                             const float* __restrict__ dis,
                                             const float* __restrict__ bias,
                                             ushort* __restrict__ Out, int n) {
    int node = blockIdx.x * 8 + (threadIdx.x >> 5);
    int lane = threadIdx.x & 31;        // 32 lanes per node, 4 features/lane
    if (node >= n) return;
    float dn = dis[node];
    int beg = row_ptr[node], end = row_ptr[node + 1];
    uint2 pw = *(const uint2*)(H + (size_t)node * DIM + lane * 4);  // self-loop row
    float a0 = dn * bflo(pw.x), a1 = dn * bfhi(pw.x);
    float a2 = dn * bflo(pw.y), a3 = dn * bfhi(pw.y);
    int e = beg;
    for (; e + 3 < end; e += 4) {
        int c0 = col[e], c1 = col[e + 1], c2 = col[e + 2], c3 = col[e + 3];
        float w0 = dis[c0], w1 = dis[c1], w2 = dis[c2], w3 = dis[c3];
        uint2 p0 = *(const uint2*)(H + (size_t)c0 * DIM + lane * 4);
        uint2 p1 = *(const uint2*)(H + (size_t)c1 * DIM + lane * 4);
        uint2 p2 = *(const uint2*)(H + (size_t)c2 * DIM + lane * 4);
        uint2 p3 = *(const uint2*)(H + (size_t)c3 * DIM + lane * 4);
        a0 += w0 * bflo(p0.x) + w1 * bflo(p1.x) + w2 * bflo(p2.x) + w3 * bflo(p3.x);
        a1 += w0 * bfhi(p0.x) + w1 * bfhi(p1.x) + w2 * bfhi(p2.x) + w3 * bfhi(p3.x);
        a2 += w0 * bflo(p0.y) + w1 * bflo(p1.y) + w2 * bflo(p2.y) + w3 * bflo(p3.y);
        a3 += w0 * bfhi(p0.y) + w1 * bfhi(p1.y) + w2 * bfhi(p2.y) + w3 * bfhi(p3.y);
    }
    for (; e < end; e++) {
        int c = col[e];
        float w = dis[c];
        uint2 p = *(const uint2*)(H + (size_t)c * DIM + lane * 4);
        a0 += w * bflo(p.x);
        a1 += w * bfhi(p.x);
        a2 += w * bflo(p.y);
        a3 += w * bfhi(p.y);
    }
    int d0 = lane * 4;
    a0 = fmaxf(a0 * dn + bias[d0], 0.f);
    a1 = fmaxf(a1 * dn + bias[d0 + 1], 0.f);
    a2 = fmaxf(a2 * dn + bias[d0 + 2], 0.f);
    a3 = fmaxf(a3 * dn + bias[d0 + 3], 0.f);
    uint o0 = (uint)f2bf(a0) | ((uint)f2bf(a1) << 16);
    uint o1 = (uint)f2bf(a2) | ((uint)f2bf(a3) << 16);
    *(uint2*)(Out + (size_t)node * DIM + d0) = make_uint2(o0, o1);
}

// ---------------- global add pool (batch_vec sorted, bf16 in, fp32 out) ----------------

__global__ void pool_k(const ushort* __restrict__ H, const int* __restrict__ batch,
                       float* Out, int n) {
    int d = threadIdx.x;
    int n0 = blockIdx.x * 64;
    int gcur = -1;
    float s = 0.f;
    for (int i = 0; i < 64; i++) {
        int node = n0 + i;
        if (node >= n) break;
        int g = batch[node];
        if (g != gcur) {
            if (gcur >= 0) atomicAdd(&Out[gcur * DIM + d], s);
            gcur = g;
            s = 0.f;
        }
        s += bflo((uint)H[(size_t)node * DIM + d]);
    }
    if (gcur >= 0) atomicAdd(&Out[gcur * DIM + d], s);
}

// ---------------- launch ----------------

extern "C" void kernel_launch(void* const* d_in, const int* in_sizes, int n_in,
                              void* d_out, int out_size, void* d_ws, size_t ws_size,
                              hipStream_t stream) {
    const float* x  = (const float*)d_in[0];
    const float* W1 = (const float*)d_in[1];
    const float* b1 = (const float*)d_in[2];
    const float* W2 = (const float*)d_in[3];
    const float* b2 = (const float*)d_in[4];
    const float* W3 = (const float*)d_in[5];
    const float* b3 = (const float*)d_in[6];
    const int*   ei = (const int*)d_in[7];
    const int*   bv = (const int*)d_in[8];
    float* out = (float*)d_out;

    const int N = N_NODES, E = N_EDGES;

    char* p = (char*)d_ws;
    auto alloc = [&](size_t bytes) -> void* {
        void* r = (void*)p;
        p += (bytes + 255) & ~(size_t)255;
        return r;
    };
    int*    bcnt_pad = (int*)alloc((size_t)NB * 16 * 4);
    int*    bcur_pad = (int*)alloc((size_t)NB * 16 * 4);
    int*    bbase    = (int*)alloc((size_t)(NB + 1) * 4);
    int*    row_ptr  = (int*)alloc((size_t)(N + 1) * 4);
    float*  dis      = (float*)alloc((size_t)N * 4);
    uint*   stage    = (uint*)alloc((size_t)E * 4);
    int*    col      = (int*)alloc((size_t)E * 4);
    ushort* B1       = (ushort*)alloc((size_t)N * DIM * 2);
    ushort* B2       = (ushort*)alloc((size_t)N * DIM * 2);

    const int* src = ei;
    const int* dst = ei + E;

    hipMemsetAsync(d_out, 0, (size_t)N_GRAPHS * DIM * sizeof(float), stream);
    hipMemsetAsync(bcnt_pad, 0, (size_t)NB * 16 * 4, stream);

    bhist_k<<<NCHUNK, 256, 0, stream>>>(dst, bcnt_pad, E);
    bscan_k<<<1, 64, 0, stream>>>(bcnt_pad, bbase, bcur_pad);
    bscat_k<<<NCHUNK, 256, 0, stream>>>(src, dst, bcur_pad, stage, E);
    csr_k<<<NB, 256, 0, stream>>>(stage, bbase, row_ptr, dis, col);

    int gemm_grid = (N + GEMM_ROWS - 1) / GEMM_ROWS;
    int agg_grid  = (N + 7) / 8;

    gemm_k<float><<<gemm_grid, 256, 0, stream>>>(x,  W1, B1, N);
    agg_k<<<agg_grid, 256, 0, stream>>>(B1, row_ptr, col, dis, b1, B2, N);

    gemm_k<ushort><<<gemm_grid, 256, 0, stream>>>(B2, W2, B1, N);
    agg_k<<<agg_grid, 256, 0, stream>>>(B1, row_ptr, col, dis, b2, B2, N);

    gemm_k<ushort><<<gemm_grid, 256, 0, stream>>>(B2, W3, B1, N);
    agg_k<<<agg_grid, 256, 0, stream>>>(B1, row_ptr, col, dis, b3, B2, N);

    pool_k<<<(N + 63) / 64, 128, 0, stream>>>(B2, bv, out, N);
}